// Round 4
// baseline (1154.596 us; speedup 1.0000x reference)
//
#include <hip/hip_runtime.h>
#include <cmath>

#define NNODES 50000
#define NEDGES 800000
#define ORIG_FEA 92
#define NBR_FEA 41
#define HID 64
#define BN_EPS 1e-5f

typedef __attribute__((ext_vector_type(8))) short short8;
typedef __attribute__((ext_vector_type(4))) float f32x4;
typedef unsigned short ushort;
typedef unsigned int uint;

static __device__ __forceinline__ ushort f2bf(float f) {
    uint u = __float_as_uint(f);
    uint r = u + 0x7fffu + ((u >> 16) & 1u);   // round-to-nearest-even
    return (ushort)(r >> 16);
}

// ---------------------------------------------------------------------------
// Fold embedding2 into per-layer edge weights:
//   Wcf[i] = W2 @ Wf[i][128:192,:], bcf[i] = bf[i] + b2 @ Wf[i][128:192,:]
//   Wcs[i] = W2 @ Ws[i][128:192,:], bcs[i] = bs[i] + b2 @ Ws[i][128:192,:]
// ---------------------------------------------------------------------------
__global__ void combine_weights(const float* __restrict__ W2, const float* __restrict__ b2,
                                const float* __restrict__ Wf, const float* __restrict__ bf,
                                const float* __restrict__ Ws, const float* __restrict__ bs,
                                float* __restrict__ Wcf, float* __restrict__ Wcs,
                                float* __restrict__ bcf, float* __restrict__ bcs) {
    int layer = blockIdx.x >> 1;
    int is_s = blockIdx.x & 1;
    const float* Wbig = (is_s ? Ws : Wf) + layer * 192 * HID + 128 * HID; // e-part
    const float* bvec = (is_s ? bs : bf) + layer * HID;
    float* Wc = (is_s ? Wcs : Wcf) + layer * NBR_FEA * HID;
    float* bc = (is_s ? bcs : bcf) + layer * HID;

    for (int idx = threadIdx.x; idx < NBR_FEA * HID; idx += blockDim.x) {
        int r = idx / HID, c = idx % HID;
        float acc = 0.f;
        for (int k = 0; k < HID; ++k) acc += W2[r * HID + k] * Wbig[k * HID + c];
        Wc[idx] = acc;
    }
    for (int c = threadIdx.x; c < HID; c += blockDim.x) {
        float acc = bvec[c];
        for (int k = 0; k < HID; ++k) acc += b2[k] * Wbig[k * HID + c];
        bc[c] = acc;
    }
}

// ---------------------------------------------------------------------------
// Pack combined B = [W_src (64 rows) ; Wc (41 rows, pad to 64)] (K=128, N=128)
// into MFMA B-fragment order:
//   Bpack[layer][t(8)][ck(4)][lane(64)][j(8)], k = ck*32 + (lane>>4)*8 + j,
//   col = (t&3)*16 + (lane&15); t<4 -> f-matrix, t>=4 -> s-matrix.
// ---------------------------------------------------------------------------
__global__ void pack_B(const float* __restrict__ Wf, const float* __restrict__ Ws,
                       const float* __restrict__ Wcf, const float* __restrict__ Wcs,
                       ushort* __restrict__ Bpack) {
    int idx = blockIdx.x * blockDim.x + threadIdx.x;
    if (idx >= 3 * 8 * 4 * 512) return;
    int j = idx & 7;
    int lane = (idx >> 3) & 63;
    int ck = (idx >> 9) & 3;
    int t = (idx >> 11) & 7;
    int layer = idx >> 14;
    int k = ck * 32 + ((lane >> 4) * 8) + j;
    int col = (t & 3) * 16 + (lane & 15);
    const float* Wbig = ((t < 4) ? Wf : Ws) + layer * 192 * HID;
    const float* Wc = ((t < 4) ? Wcf : Wcs) + layer * NBR_FEA * HID;
    float v;
    if (k < 64) v = Wbig[(64 + k) * HID + col];
    else if (k - 64 < NBR_FEA) v = Wc[(k - 64) * HID + col];
    else v = 0.f;
    Bpack[idx] = f2bf(v);
}

// ---------------------------------------------------------------------------
// CSR build: histogram -> scan -> scatter (gather-form for ea)
// ---------------------------------------------------------------------------
__global__ void k_hist(const int* __restrict__ eidx, int* __restrict__ deg) {
    int e = blockIdx.x * blockDim.x + threadIdx.x;
    if (e < NEDGES) atomicAdd(&deg[eidx[NEDGES + e]], 1);
}

__global__ void k_blocksum(const int* __restrict__ deg, int* __restrict__ bsum) {
    __shared__ int sh[256];
    int i = blockIdx.x * 256 + threadIdx.x;
    sh[threadIdx.x] = (i < NNODES) ? deg[i] : 0;
    __syncthreads();
    for (int s = 128; s > 0; s >>= 1) {
        if (threadIdx.x < s) sh[threadIdx.x] += sh[threadIdx.x + s];
        __syncthreads();
    }
    if (threadIdx.x == 0) bsum[blockIdx.x] = sh[0];
}

__global__ void k_scanbase(const int* __restrict__ bsum, int* __restrict__ bbase,
                           int* __restrict__ rowptr) {
    __shared__ int sh[256];
    int t = threadIdx.x;
    int v = (t < 196) ? bsum[t] : 0;
    sh[t] = v;
    __syncthreads();
    for (int s = 1; s < 256; s <<= 1) {
        int add = (t >= s) ? sh[t - s] : 0;
        __syncthreads();
        sh[t] += add;
        __syncthreads();
    }
    if (t < 196) bbase[t] = sh[t] - v;   // exclusive
    if (t == 0) rowptr[NNODES] = NEDGES;
}

__global__ void k_writerow(const int* __restrict__ deg, const int* __restrict__ bbase,
                           int* __restrict__ rowptr, int* __restrict__ cursor) {
    __shared__ int sh[256];
    int t = threadIdx.x;
    int i = blockIdx.x * 256 + t;
    int v = (i < NNODES) ? deg[i] : 0;
    sh[t] = v;
    __syncthreads();
    for (int s = 1; s < 256; s <<= 1) {
        int add = (t >= s) ? sh[t - s] : 0;
        __syncthreads();
        sh[t] += add;
        __syncthreads();
    }
    if (i < NNODES) {
        int e = bbase[blockIdx.x] + sh[t] - v;
        rowptr[i] = e;
        cursor[i] = e;
    }
}

__global__ void k_scatterA(const int* __restrict__ eidx, int* __restrict__ cursor,
                           int* __restrict__ eorig, int* __restrict__ srcs) {
    int e = blockIdx.x * blockDim.x + threadIdx.x;
    if (e < NEDGES) {
        int tgt = eidx[NEDGES + e];
        int pos = atomicAdd(&cursor[tgt], 1);
        eorig[pos] = e;
        srcs[pos] = eidx[e];
    }
}

// gather-form: sequential write of sorted bf16 ea rows, random read of ea
__global__ void k_scatterB(const float* __restrict__ ea, const int* __restrict__ eorig,
                           ushort* __restrict__ eab_s) {
    long idx = (long)blockIdx.x * blockDim.x + threadIdx.x;
    if (idx >= (long)NEDGES * 8) return;
    int pos = (int)(idx >> 3);
    int j = (int)(idx & 7);
    int e = eorig[pos];
    uint w[4];
    #pragma unroll
    for (int m = 0; m < 4; ++m) {
        int k0 = j * 8 + m * 2, k1 = k0 + 1;
        uint u0 = (k0 < NBR_FEA) ? (uint)f2bf(ea[(long)e * NBR_FEA + k0]) : 0u;
        uint u1 = (k1 < NBR_FEA) ? (uint)f2bf(ea[(long)e * NBR_FEA + k1]) : 0u;
        w[m] = u0 | (u1 << 16);
    }
    uint4 o; o.x = w[0]; o.y = w[1]; o.z = w[2]; o.w = w[3];
    *(uint4*)(eab_s + (long)pos * 64 + j * 8) = o;
}

// ---------------------------------------------------------------------------
// embed + layer-0 target projection fused:
//   h = x@W1 + b1 (fp32 + bf16 copies), then
//   Ttgt[n][0:64] = h@Wf0[0:64] + bcf0, Ttgt[n][64:128] = h@Ws0[0:64] + bcs0
// One wave per node; y row broadcast via __shfl.
// ---------------------------------------------------------------------------
__global__ void embed_proj(const float* __restrict__ x, const float* __restrict__ W1,
                           const float* __restrict__ b1,
                           const float* __restrict__ Wf, const float* __restrict__ Ws,
                           const float* __restrict__ bcf, const float* __restrict__ bcs,
                           float* __restrict__ h, ushort* __restrict__ h_bf,
                           float* __restrict__ Ttgt) {
    __shared__ float Wl[2][HID][HID]; // 32 KB, layer-0 tgt blocks
    for (int idx = threadIdx.x; idx < HID * HID; idx += blockDim.x) {
        Wl[0][0][idx] = Wf[idx];   // rows 0..63 of layer 0
        Wl[1][0][idx] = Ws[idx];
    }
    __syncthreads();
    int lane = threadIdx.x & 63;
    int wid = (blockIdx.x * blockDim.x + threadIdx.x) >> 6;
    int nw = (gridDim.x * blockDim.x) >> 6;
    float bF = bcf[lane], bS = bcs[lane], b1v = b1[lane];
    for (int n = wid; n < NNODES; n += nw) {
        float acc = b1v;
        const float* xr = x + (long)n * ORIG_FEA;
        #pragma unroll 4
        for (int k = 0; k < ORIG_FEA; ++k) acc = fmaf(xr[k], W1[k * HID + lane], acc);
        h[n * HID + lane] = acc;
        h_bf[n * HID + lane] = f2bf(acc);
        float af = bF, as = bS;
        #pragma unroll 8
        for (int k = 0; k < HID; ++k) {
            float yk = __shfl(acc, k, 64);
            af = fmaf(yk, Wl[0][k][lane], af);
            as = fmaf(yk, Wl[1][k][lane], as);
        }
        Ttgt[(long)n * 128 + lane] = af;
        Ttgt[(long)n * 128 + 64 + lane] = as;
    }
}

// ---------------------------------------------------------------------------
// Edge kernel, CSR + split channels across a wave PAIR (same block):
// wave half h owns output tiles {2h, 2h+1} (gate) and {4+2h, 5+2h} (softplus)
// = channels 32h..32h+31. B regs: 4x4 frags = 64 VGPR. Per 16-edge chunk:
// A = [h_bf[src] | ea_sorted], 16 MFMA per wave. Epilogue: +Ttgt, activation,
// masked in-register accumulate; butterfly; one 128 B store per target-half.
// Also accumulates BN stats (sum, sumsq of h+agg) -> 2 atomics/lane at end.
// ---------------------------------------------------------------------------
__global__ __launch_bounds__(256, 4) void edge_kernel(
    const ushort* __restrict__ eab_s, const int* __restrict__ srcs,
    const int* __restrict__ rowptr, const ushort* __restrict__ h_bf,
    const float* __restrict__ h, const float* __restrict__ Ttgt,
    const ushort* __restrict__ Bpack, float* __restrict__ agg,
    float* __restrict__ stats) {
    int lane = threadIdx.x & 63;
    int q = lane >> 4;
    int wid = (blockIdx.x * blockDim.x + threadIdx.x) >> 6;
    int half = wid & 1;
    int pair = wid >> 1;
    int npairs = (gridDim.x * blockDim.x) >> 7;

    short8 B[4][4];
    #pragma unroll
    for (int tt = 0; tt < 4; ++tt) {
        int t = ((tt < 2) ? 0 : 4) + 2 * half + (tt & 1);
        #pragma unroll
        for (int ck = 0; ck < 4; ++ck)
            B[tt][ck] = *(const short8*)(Bpack + ((t * 4 + ck) * 512 + lane * 8));
    }

    float st1 = 0.f, st2 = 0.f;
    for (int tn = pair; tn < NNODES; tn += npairs) {
        int r0 = rowptr[tn], r1 = rowptr[tn + 1];
        int d = r1 - r0;
        float vs0 = 0.f, vs1 = 0.f;
        if (d > 0) {
            const float* tp = Ttgt + (long)tn * 128 + 32 * half + (lane & 15);
            float tf0 = tp[0], tf1 = tp[16], ts0 = tp[64], ts1 = tp[80];
            int elast = r1 - 1;
            for (int cs = 0; cs < d; cs += 16) {
                int ei = r0 + cs + (lane & 15);
                if (ei > elast) ei = elast;           // clamp padded rows
                int sv = srcs[ei];
                const short8* hrow = (const short8*)(h_bf + (long)sv * 64);
                const short8* erow = (const short8*)(eab_s + (long)ei * 64);
                short8 A0 = hrow[q], A1 = hrow[4 + q];
                short8 A2 = erow[q], A3 = erow[4 + q];

                f32x4 accf0, accf1, accs0, accs1;
                f32x4 z = {0.f, 0.f, 0.f, 0.f};
                accf0 = __builtin_amdgcn_mfma_f32_16x16x32_bf16(A0, B[0][0], z, 0, 0, 0);
                accf1 = __builtin_amdgcn_mfma_f32_16x16x32_bf16(A0, B[1][0], z, 0, 0, 0);
                accs0 = __builtin_amdgcn_mfma_f32_16x16x32_bf16(A0, B[2][0], z, 0, 0, 0);
                accs1 = __builtin_amdgcn_mfma_f32_16x16x32_bf16(A0, B[3][0], z, 0, 0, 0);
                accf0 = __builtin_amdgcn_mfma_f32_16x16x32_bf16(A1, B[0][1], accf0, 0, 0, 0);
                accf1 = __builtin_amdgcn_mfma_f32_16x16x32_bf16(A1, B[1][1], accf1, 0, 0, 0);
                accs0 = __builtin_amdgcn_mfma_f32_16x16x32_bf16(A1, B[2][1], accs0, 0, 0, 0);
                accs1 = __builtin_amdgcn_mfma_f32_16x16x32_bf16(A1, B[3][1], accs1, 0, 0, 0);
                accf0 = __builtin_amdgcn_mfma_f32_16x16x32_bf16(A2, B[0][2], accf0, 0, 0, 0);
                accf1 = __builtin_amdgcn_mfma_f32_16x16x32_bf16(A2, B[1][2], accf1, 0, 0, 0);
                accs0 = __builtin_amdgcn_mfma_f32_16x16x32_bf16(A2, B[2][2], accs0, 0, 0, 0);
                accs1 = __builtin_amdgcn_mfma_f32_16x16x32_bf16(A2, B[3][2], accs1, 0, 0, 0);
                accf0 = __builtin_amdgcn_mfma_f32_16x16x32_bf16(A3, B[0][3], accf0, 0, 0, 0);
                accf1 = __builtin_amdgcn_mfma_f32_16x16x32_bf16(A3, B[1][3], accf1, 0, 0, 0);
                accs0 = __builtin_amdgcn_mfma_f32_16x16x32_bf16(A3, B[2][3], accs0, 0, 0, 0);
                accs1 = __builtin_amdgcn_mfma_f32_16x16x32_bf16(A3, B[3][3], accs1, 0, 0, 0);

                #pragma unroll
                for (int r = 0; r < 4; ++r) {
                    bool valid = (cs + q * 4 + r) < d;
                    float f0 = accf0[r] + tf0, s0 = accs0[r] + ts0;
                    float f1 = accf1[r] + tf1, s1 = accs1[r] + ts1;
                    float g0 = __builtin_amdgcn_rcpf(1.f + __expf(-f0));
                    float g1 = __builtin_amdgcn_rcpf(1.f + __expf(-f1));
                    float p0 = fmaxf(s0, 0.f) + __logf(1.f + __expf(-fabsf(s0)));
                    float p1 = fmaxf(s1, 0.f) + __logf(1.f + __expf(-fabsf(s1)));
                    vs0 += valid ? g0 * p0 : 0.f;
                    vs1 += valid ? g1 * p1 : 0.f;
                }
            }
            vs0 += __shfl_xor(vs0, 16, 64); vs0 += __shfl_xor(vs0, 32, 64);
            vs1 += __shfl_xor(vs1, 16, 64); vs1 += __shfl_xor(vs1, 32, 64);
        }
        if (lane < 32) {
            float out = (lane < 16) ? vs0 : vs1;   // ch = 32*half + lane
            int ch = 32 * half + lane;
            agg[(long)tn * 64 + ch] = out;
            float v = h[(long)tn * 64 + ch] + out;
            st1 += v;
            st2 = fmaf(v, v, st2);
        }
    }
    if (lane < 32) {
        int ch = 32 * half + lane;
        atomicAdd(&stats[ch], st1);
        atomicAdd(&stats[64 + ch], st2);
    }
}

// ---------------------------------------------------------------------------
// BN apply (+ReLU) + NEXT layer's target projection, fused. One wave/node.
//   y = BN(h + agg)[*gamma+beta][relu] -> h, h_bf
//   if next_layer >= 0: Ttgt[n] = [y@Wf_next[0:64]+bcf | y@Ws_next[0:64]+bcs]
// ---------------------------------------------------------------------------
__global__ __launch_bounds__(256) void bn_apply_proj(
    float* __restrict__ h, const float* __restrict__ agg,
    const float* __restrict__ stats, const float* __restrict__ gamma,
    const float* __restrict__ beta, ushort* __restrict__ h_bf,
    const float* __restrict__ Wf, const float* __restrict__ Ws,
    const float* __restrict__ bcf, const float* __restrict__ bcs,
    float* __restrict__ Ttgt, int relu, int next_layer) {
    __shared__ float Wl[2][HID][HID]; // 32 KB
    if (next_layer >= 0) {
        const float* Wfb = Wf + (long)next_layer * 192 * HID;
        const float* Wsb = Ws + (long)next_layer * 192 * HID;
        for (int idx = threadIdx.x; idx < HID * HID; idx += blockDim.x) {
            Wl[0][0][idx] = Wfb[idx];
            Wl[1][0][idx] = Wsb[idx];
        }
        __syncthreads();
    }
    int lane = threadIdx.x & 63;
    int wid = (blockIdx.x * blockDim.x + threadIdx.x) >> 6;
    int nw = (gridDim.x * blockDim.x) >> 6;
    const float invn = 1.f / (float)NNODES;
    float mean = stats[lane] * invn;
    float var = stats[64 + lane] * invn - mean * mean;
    float rs = rsqrtf(var + BN_EPS);
    float ga = gamma[lane], be = beta[lane];
    float bF = 0.f, bS = 0.f;
    if (next_layer >= 0) {
        bF = bcf[next_layer * HID + lane];
        bS = bcs[next_layer * HID + lane];
    }
    for (int n = wid; n < NNODES; n += nw) {
        float v = h[n * HID + lane] + agg[n * HID + lane];
        float y = (v - mean) * rs * ga + be;
        if (relu) y = fmaxf(y, 0.f);
        h[n * HID + lane] = y;
        h_bf[n * HID + lane] = f2bf(y);
        if (next_layer >= 0) {
            float af = bF, as = bS;
            #pragma unroll 8
            for (int k = 0; k < HID; ++k) {
                float yk = __shfl(y, k, 64);
                af = fmaf(yk, Wl[0][k][lane], af);
                as = fmaf(yk, Wl[1][k][lane], as);
            }
            Ttgt[(long)n * 128 + lane] = af;
            Ttgt[(long)n * 128 + 64 + lane] = as;
        }
    }
}

extern "C" void kernel_launch(void* const* d_in, const int* in_sizes, int n_in,
                              void* d_out, int out_size, void* d_ws, size_t ws_size,
                              hipStream_t stream) {
    const float* x    = (const float*)d_in[0];
    const float* ea   = (const float*)d_in[1];
    const int*   eidx = (const int*)d_in[2];
    const float* W1   = (const float*)d_in[3];
    const float* b1   = (const float*)d_in[4];
    const float* W2   = (const float*)d_in[5];
    const float* b2   = (const float*)d_in[6];
    const float* Wf   = (const float*)d_in[7];
    const float* bf   = (const float*)d_in[8];
    const float* Ws   = (const float*)d_in[9];
    const float* bs   = (const float*)d_in[10];
    const float* gamma= (const float*)d_in[11];
    const float* beta = (const float*)d_in[12];
    float* h = (float*)d_out; // [NNODES, 64]

    // workspace layout (256 B aligned sections)
    char* wb = (char*)d_ws;
    auto align = [&]() { wb = (char*)(((size_t)wb + 255) & ~(size_t)255); };
    ushort* Bpack = (ushort*)wb;  wb += 3 * 8 * 4 * 512 * sizeof(ushort); align(); // 96 KB
    float* Wcf   = (float*)wb;    wb += 3 * NBR_FEA * HID * sizeof(float);
    float* Wcs   = (float*)wb;    wb += 3 * NBR_FEA * HID * sizeof(float);
    float* bcf   = (float*)wb;    wb += 3 * HID * sizeof(float);
    float* bcs   = (float*)wb;    wb += 3 * HID * sizeof(float);
    float* stats = (float*)wb;    wb += 2 * HID * sizeof(float); align();
    int* deg     = (int*)wb;      wb += NNODES * sizeof(int);
    int* rowptr  = (int*)wb;      wb += (NNODES + 1) * sizeof(int);
    int* cursor  = (int*)wb;      wb += NNODES * sizeof(int);
    int* bsum    = (int*)wb;      wb += 256 * sizeof(int);
    int* bbase   = (int*)wb;      wb += 256 * sizeof(int); align();
    int* eorig   = (int*)wb;      wb += NEDGES * sizeof(int);          // 3.2 MB
    int* srcs    = (int*)wb;      wb += NEDGES * sizeof(int);          // 3.2 MB
    align();
    float* Ttgt  = (float*)wb;    wb += (size_t)NNODES * 128 * sizeof(float); // 25.6 MB
    float* agg   = (float*)wb;    wb += (size_t)NNODES * HID * sizeof(float); // 12.8 MB
    ushort* h_bf = (ushort*)wb;   wb += (size_t)NNODES * HID * sizeof(ushort); // 6.4 MB
    ushort* eab_s= (ushort*)wb;   wb += (size_t)NEDGES * 64 * sizeof(ushort);  // 102.4 MB

    // --- setup: weights, CSR sort, embed+proj0 ---
    combine_weights<<<6, 256, 0, stream>>>(W2, b2, Wf, bf, Ws, bs, Wcf, Wcs, bcf, bcs);
    pack_B<<<(3 * 8 * 4 * 512 + 255) / 256, 256, 0, stream>>>(Wf, Ws, Wcf, Wcs, Bpack);

    hipMemsetAsync(deg, 0, NNODES * sizeof(int), stream);
    k_hist<<<(NEDGES + 255) / 256, 256, 0, stream>>>(eidx, deg);
    k_blocksum<<<196, 256, 0, stream>>>(deg, bsum);
    k_scanbase<<<1, 256, 0, stream>>>(bsum, bbase, rowptr);
    k_writerow<<<196, 256, 0, stream>>>(deg, bbase, rowptr, cursor);
    k_scatterA<<<(NEDGES + 255) / 256, 256, 0, stream>>>(eidx, cursor, eorig, srcs);
    k_scatterB<<<(NEDGES * 8 + 255) / 256, 256, 0, stream>>>(ea, eorig, eab_s);

    embed_proj<<<1024, 256, 0, stream>>>(x, W1, b1, Wf, Ws, bcf, bcs, h, h_bf, Ttgt);

    for (int i = 0; i < 3; ++i) {
        hipMemsetAsync(stats, 0, 2 * HID * sizeof(float), stream);
        edge_kernel<<<2048, 256, 0, stream>>>(eab_s, srcs, rowptr, h_bf, h, Ttgt,
                                              Bpack + i * 16384, agg, stats);
        bn_apply_proj<<<1024, 256, 0, stream>>>(h, agg, stats, gamma + i * HID,
                                                beta + i * HID, h_bf, Wf, Ws, bcf, bcs,
                                                Ttgt, (i < 2) ? 1 : 0,
                                                (i < 2) ? (i + 1) : -1);
    }
}

// Round 5
// 1084.782 us; speedup vs baseline: 1.0644x; 1.0644x over previous
//
#include <hip/hip_runtime.h>
#include <cmath>

#define NNODES 50000
#define NEDGES 800000
#define ORIG_FEA 92
#define NBR_FEA 41
#define HID 64
#define BN_EPS 1e-5f

typedef __attribute__((ext_vector_type(8))) short short8;
typedef __attribute__((ext_vector_type(4))) float f32x4;
typedef unsigned short ushort;
typedef unsigned int uint;

static __device__ __forceinline__ ushort f2bf(float f) {
    uint u = __float_as_uint(f);
    uint r = u + 0x7fffu + ((u >> 16) & 1u);   // round-to-nearest-even
    return (ushort)(r >> 16);
}

// ---------------------------------------------------------------------------
// prep: everything weight-side in ONE kernel.
// Blocks 0..5 = (layer, f/s): pack B = [W_src(64 rows); W2@We (41 rows, pad 64)]
// (K=128, N=64 per half) into MFMA B-fragment order
//   Bpack[layer][t(8)][ck(4)][lane(64)][j(8)], k = ck*32+(lane>>4)*8+j,
//   col = (t&3)*16+(lane&15); t<4 f-matrix, t>=4 s-matrix.
// Wc computed on the fly (64-FMA dot per element). Also bcf/bcs biases.
// Block 6: zero the 3 per-layer BN stats slots.
// ---------------------------------------------------------------------------
__global__ void prep(const float* __restrict__ W2, const float* __restrict__ b2,
                     const float* __restrict__ Wf, const float* __restrict__ bf,
                     const float* __restrict__ Ws, const float* __restrict__ bs,
                     ushort* __restrict__ Bpack, float* __restrict__ bcf,
                     float* __restrict__ bcs, float* __restrict__ stats) {
    if (blockIdx.x == 6) {
        for (int i = threadIdx.x; i < 3 * 128; i += blockDim.x) stats[i] = 0.f;
        return;
    }
    int layer = blockIdx.x >> 1;
    int fs = blockIdx.x & 1;
    const float* Wbig = (fs ? Ws : Wf) + layer * 192 * HID;
    const float* We = Wbig + 128 * HID;                 // e-part rows
    const float* bvec = (fs ? bs : bf) + layer * HID;
    float* bc = (fs ? bcs : bcf) + layer * HID;
    ushort* Bp = Bpack + layer * 16384 + fs * 8192;     // t = fs*4 + tt

    for (int idx = threadIdx.x; idx < 8192; idx += blockDim.x) {
        int j = idx & 7;
        int lane = (idx >> 3) & 63;
        int ck = (idx >> 9) & 3;
        int tt = (idx >> 11) & 3;
        int k = ck * 32 + ((lane >> 4) * 8) + j;
        int col = tt * 16 + (lane & 15);
        float v = 0.f;
        if (k < 64) v = Wbig[(64 + k) * HID + col];
        else if (k < 64 + NBR_FEA) {
            int r = k - 64;
            float a = 0.f;
            for (int m = 0; m < HID; ++m) a += W2[r * HID + m] * We[m * HID + col];
            v = a;
        }
        Bp[(tt * 4 + ck) * 512 + lane * 8 + j] = f2bf(v);
    }
    for (int c0 = threadIdx.x; c0 < HID; c0 += blockDim.x) {
        float a = bvec[c0];
        for (int m = 0; m < HID; ++m) a += b2[m] * We[m * HID + c0];
        bc[c0] = a;
    }
}

// ---------------------------------------------------------------------------
// CSR build: histogram -> scan -> scatter (gather-form for ea)
// ---------------------------------------------------------------------------
__global__ void k_hist(const int* __restrict__ eidx, int* __restrict__ deg) {
    int e = blockIdx.x * blockDim.x + threadIdx.x;
    if (e < NEDGES) atomicAdd(&deg[eidx[NEDGES + e]], 1);
}

__global__ void k_blocksum(const int* __restrict__ deg, int* __restrict__ bsum) {
    __shared__ int sh[256];
    int i = blockIdx.x * 256 + threadIdx.x;
    sh[threadIdx.x] = (i < NNODES) ? deg[i] : 0;
    __syncthreads();
    for (int s = 128; s > 0; s >>= 1) {
        if (threadIdx.x < s) sh[threadIdx.x] += sh[threadIdx.x + s];
        __syncthreads();
    }
    if (threadIdx.x == 0) bsum[blockIdx.x] = sh[0];
}

__global__ void k_scanbase(const int* __restrict__ bsum, int* __restrict__ bbase,
                           int* __restrict__ rowptr) {
    __shared__ int sh[256];
    int t = threadIdx.x;
    int v = (t < 196) ? bsum[t] : 0;
    sh[t] = v;
    __syncthreads();
    for (int s = 1; s < 256; s <<= 1) {
        int add = (t >= s) ? sh[t - s] : 0;
        __syncthreads();
        sh[t] += add;
        __syncthreads();
    }
    if (t < 196) bbase[t] = sh[t] - v;   // exclusive
    if (t == 0) rowptr[NNODES] = NEDGES;
}

__global__ void k_writerow(const int* __restrict__ deg, const int* __restrict__ bbase,
                           int* __restrict__ rowptr, int* __restrict__ cursor) {
    __shared__ int sh[256];
    int t = threadIdx.x;
    int i = blockIdx.x * 256 + t;
    int v = (i < NNODES) ? deg[i] : 0;
    sh[t] = v;
    __syncthreads();
    for (int s = 1; s < 256; s <<= 1) {
        int add = (t >= s) ? sh[t - s] : 0;
        __syncthreads();
        sh[t] += add;
        __syncthreads();
    }
    if (i < NNODES) {
        int e = bbase[blockIdx.x] + sh[t] - v;
        rowptr[i] = e;
        cursor[i] = e;
    }
}

__global__ void k_scatterA(const int* __restrict__ eidx, int* __restrict__ cursor,
                           int* __restrict__ eorig, int* __restrict__ srcs) {
    int e = blockIdx.x * blockDim.x + threadIdx.x;
    if (e < NEDGES) {
        int tgt = eidx[NEDGES + e];
        int pos = atomicAdd(&cursor[tgt], 1);
        eorig[pos] = e;
        srcs[pos] = eidx[e];
    }
}

// gather-form: sequential write of sorted bf16 ea rows, random read of ea
__global__ void k_scatterB(const float* __restrict__ ea, const int* __restrict__ eorig,
                           ushort* __restrict__ eab_s) {
    long idx = (long)blockIdx.x * blockDim.x + threadIdx.x;
    if (idx >= (long)NEDGES * 8) return;
    int pos = (int)(idx >> 3);
    int j = (int)(idx & 7);
    int e = eorig[pos];
    uint w[4];
    #pragma unroll
    for (int m = 0; m < 4; ++m) {
        int k0 = j * 8 + m * 2, k1 = k0 + 1;
        uint u0 = (k0 < NBR_FEA) ? (uint)f2bf(ea[(long)e * NBR_FEA + k0]) : 0u;
        uint u1 = (k1 < NBR_FEA) ? (uint)f2bf(ea[(long)e * NBR_FEA + k1]) : 0u;
        w[m] = u0 | (u1 << 16);
    }
    uint4 o; o.x = w[0]; o.y = w[1]; o.z = w[2]; o.w = w[3];
    *(uint4*)(eab_s + (long)pos * 64 + j * 8) = o;
}

// ---------------------------------------------------------------------------
// Ttgt permuted layout: gate ch stored at (ch&15)*4+(ch>>4), softplus at 64+same.
// Edge epilogue then reads exactly 2 float4 per lane.
// ---------------------------------------------------------------------------

// embed + layer-0 target projection fused (one wave per node, shfl broadcast)
__global__ void embed_proj(const float* __restrict__ x, const float* __restrict__ W1,
                           const float* __restrict__ b1,
                           const float* __restrict__ Wf, const float* __restrict__ Ws,
                           const float* __restrict__ bcf, const float* __restrict__ bcs,
                           float* __restrict__ h, ushort* __restrict__ h_bf,
                           float* __restrict__ Ttgt) {
    __shared__ float Wl[2][HID][HID]; // 32 KB, layer-0 tgt blocks
    for (int idx = threadIdx.x; idx < HID * HID; idx += blockDim.x) {
        Wl[0][0][idx] = Wf[idx];   // rows 0..63 of layer 0
        Wl[1][0][idx] = Ws[idx];
    }
    __syncthreads();
    int lane = threadIdx.x & 63;
    int wid = (blockIdx.x * blockDim.x + threadIdx.x) >> 6;
    int nw = (gridDim.x * blockDim.x) >> 6;
    int pg = (lane & 15) * 4 + (lane >> 4);   // permuted position for channel=lane
    float bF = bcf[lane], bS = bcs[lane], b1v = b1[lane];
    for (int n = wid; n < NNODES; n += nw) {
        float acc = b1v;
        const float* xr = x + (long)n * ORIG_FEA;
        #pragma unroll 4
        for (int k = 0; k < ORIG_FEA; ++k) acc = fmaf(xr[k], W1[k * HID + lane], acc);
        h[n * HID + lane] = acc;
        h_bf[n * HID + lane] = f2bf(acc);
        float af = bF, as = bS;
        #pragma unroll 8
        for (int k = 0; k < HID; ++k) {
            float yk = __shfl(acc, k, 64);
            af = fmaf(yk, Wl[0][k][lane], af);
            as = fmaf(yk, Wl[1][k][lane], as);
        }
        Ttgt[(long)n * 128 + pg] = af;
        Ttgt[(long)n * 128 + 64 + pg] = as;
    }
}

// ---------------------------------------------------------------------------
// Edge kernel: ONE WAVE PER TARGET, software-pipelined.
// Prefetch (rowptr, first-chunk srcs, Ttgt float4 x2) for tn+stride during
// compute of tn. Per 16-edge chunk: A = [h_bf[src] | eab_sorted], 32 MFMA.
// Epilogue: +Ttgt (vector), sigmoid*softplus, masked in-register accumulate;
// butterfly; one 256 B store per target. BN stats fused, block-reduced,
// 2 atomics/lane/block.
// ---------------------------------------------------------------------------
__global__ __launch_bounds__(256, 2) void edge_kernel(
    const ushort* __restrict__ eab_s, const int* __restrict__ srcs,
    const int* __restrict__ rowptr, const ushort* __restrict__ h_bf,
    const float* __restrict__ h, const float* __restrict__ Ttgt,
    const ushort* __restrict__ Bpack, float* __restrict__ agg,
    float* __restrict__ stats) {
    int lane = threadIdx.x & 63;
    int q = lane >> 4;
    int c = lane & 15;
    int wid = (blockIdx.x * blockDim.x + threadIdx.x) >> 6;
    int nw = (gridDim.x * blockDim.x) >> 6;

    short8 B[8][4];
    #pragma unroll
    for (int t = 0; t < 8; ++t)
        #pragma unroll
        for (int ck = 0; ck < 4; ++ck)
            B[t][ck] = *(const short8*)(Bpack + ((t * 4 + ck) * 512 + lane * 8));

    float st1 = 0.f, st2 = 0.f;
    int tn = wid;
    int r0 = 0, r1 = 0, sv0 = 0;
    f32x4 tf = {0.f, 0.f, 0.f, 0.f}, ts = {0.f, 0.f, 0.f, 0.f};
    if (tn < NNODES) {
        r0 = rowptr[tn]; r1 = rowptr[tn + 1];
        int e = r0 + c; if (e > NEDGES - 1) e = NEDGES - 1;
        sv0 = srcs[e];
        tf = *(const f32x4*)(Ttgt + (long)tn * 128 + 4 * c);
        ts = *(const f32x4*)(Ttgt + (long)tn * 128 + 64 + 4 * c);
    }

    while (tn < NNODES) {
        int tn2 = tn + nw;
        int r0n = 0, r1n = 0, svn = 0;
        f32x4 tfn = {0.f, 0.f, 0.f, 0.f}, tsn = {0.f, 0.f, 0.f, 0.f};
        if (tn2 < NNODES) {                       // prefetch next target
            r0n = rowptr[tn2]; r1n = rowptr[tn2 + 1];
            int e = r0n + c; if (e > NEDGES - 1) e = NEDGES - 1;
            svn = srcs[e];
            tfn = *(const f32x4*)(Ttgt + (long)tn2 * 128 + 4 * c);
            tsn = *(const f32x4*)(Ttgt + (long)tn2 * 128 + 64 + 4 * c);
        }

        int d = r1 - r0;
        float vs0 = 0.f, vs1 = 0.f, vs2 = 0.f, vs3 = 0.f;
        if (d > 0) {
            int sv = sv0;
            for (int cs = 0; cs < d; cs += 16) {
                int ei = r0 + cs + c; if (ei > NEDGES - 1) ei = NEDGES - 1;
                if (cs) sv = srcs[ei];
                const short8* hrow = (const short8*)(h_bf + (long)sv * 64);
                const short8* erow = (const short8*)(eab_s + (long)ei * 64);
                short8 A0 = hrow[q], A1 = hrow[4 + q];
                short8 A2 = erow[q], A3 = erow[4 + q];

                f32x4 accf[4], accs[4];
                f32x4 z = {0.f, 0.f, 0.f, 0.f};
                #pragma unroll
                for (int t = 0; t < 4; ++t) {
                    accf[t] = __builtin_amdgcn_mfma_f32_16x16x32_bf16(A0, B[t][0], z, 0, 0, 0);
                    accs[t] = __builtin_amdgcn_mfma_f32_16x16x32_bf16(A0, B[t + 4][0], z, 0, 0, 0);
                }
                #pragma unroll
                for (int t = 0; t < 4; ++t) {
                    accf[t] = __builtin_amdgcn_mfma_f32_16x16x32_bf16(A1, B[t][1], accf[t], 0, 0, 0);
                    accs[t] = __builtin_amdgcn_mfma_f32_16x16x32_bf16(A1, B[t + 4][1], accs[t], 0, 0, 0);
                }
                #pragma unroll
                for (int t = 0; t < 4; ++t) {
                    accf[t] = __builtin_amdgcn_mfma_f32_16x16x32_bf16(A2, B[t][2], accf[t], 0, 0, 0);
                    accs[t] = __builtin_amdgcn_mfma_f32_16x16x32_bf16(A2, B[t + 4][2], accs[t], 0, 0, 0);
                }
                #pragma unroll
                for (int t = 0; t < 4; ++t) {
                    accf[t] = __builtin_amdgcn_mfma_f32_16x16x32_bf16(A3, B[t][3], accf[t], 0, 0, 0);
                    accs[t] = __builtin_amdgcn_mfma_f32_16x16x32_bf16(A3, B[t + 4][3], accs[t], 0, 0, 0);
                }

                #pragma unroll
                for (int r = 0; r < 4; ++r) {
                    bool valid = (cs + q * 4 + r) < d;
                    #pragma unroll
                    for (int t = 0; t < 4; ++t) {
                        float f = accf[t][r] + tf[t];
                        float s = accs[t][r] + ts[t];
                        float g = __builtin_amdgcn_rcpf(1.f + __expf(-f));
                        float sp = fmaxf(s, 0.f) + __logf(1.f + __expf(-fabsf(s)));
                        float msg = valid ? g * sp : 0.f;
                        if (t == 0) vs0 += msg;
                        else if (t == 1) vs1 += msg;
                        else if (t == 2) vs2 += msg;
                        else vs3 += msg;
                    }
                }
            }
            vs0 += __shfl_xor(vs0, 16, 64); vs0 += __shfl_xor(vs0, 32, 64);
            vs1 += __shfl_xor(vs1, 16, 64); vs1 += __shfl_xor(vs1, 32, 64);
            vs2 += __shfl_xor(vs2, 16, 64); vs2 += __shfl_xor(vs2, 32, 64);
            vs3 += __shfl_xor(vs3, 16, 64); vs3 += __shfl_xor(vs3, 32, 64);
        }
        float out = (q == 0) ? vs0 : (q == 1) ? vs1 : (q == 2) ? vs2 : vs3;
        agg[(long)tn * 64 + lane] = out;           // channel = q*16+c = lane
        float v = h[(long)tn * 64 + lane] + out;
        st1 += v;
        st2 = fmaf(v, v, st2);

        tn = tn2; r0 = r0n; r1 = r1n; sv0 = svn; tf = tfn; ts = tsn;
    }

    // block-level stats reduction -> 2 atomics/lane/block
    __shared__ float ls[4][64], lq[4][64];
    int w = threadIdx.x >> 6;
    ls[w][lane] = st1; lq[w][lane] = st2;
    __syncthreads();
    if (threadIdx.x < 64) {
        float t1 = ls[0][lane] + ls[1][lane] + ls[2][lane] + ls[3][lane];
        float t2 = lq[0][lane] + lq[1][lane] + lq[2][lane] + lq[3][lane];
        atomicAdd(&stats[lane], t1);
        atomicAdd(&stats[64 + lane], t2);
    }
}

// ---------------------------------------------------------------------------
// BN apply (+ReLU) + NEXT layer's target projection, fused. One wave/node.
// ---------------------------------------------------------------------------
__global__ __launch_bounds__(256) void bn_apply_proj(
    float* __restrict__ h, const float* __restrict__ agg,
    const float* __restrict__ stats, const float* __restrict__ gamma,
    const float* __restrict__ beta, ushort* __restrict__ h_bf,
    const float* __restrict__ Wf, const float* __restrict__ Ws,
    const float* __restrict__ bcf, const float* __restrict__ bcs,
    float* __restrict__ Ttgt, int relu, int next_layer) {
    __shared__ float Wl[2][HID][HID]; // 32 KB
    if (next_layer >= 0) {
        const float* Wfb = Wf + (long)next_layer * 192 * HID;
        const float* Wsb = Ws + (long)next_layer * 192 * HID;
        for (int idx = threadIdx.x; idx < HID * HID; idx += blockDim.x) {
            Wl[0][0][idx] = Wfb[idx];
            Wl[1][0][idx] = Wsb[idx];
        }
        __syncthreads();
    }
    int lane = threadIdx.x & 63;
    int wid = (blockIdx.x * blockDim.x + threadIdx.x) >> 6;
    int nw = (gridDim.x * blockDim.x) >> 6;
    int pg = (lane & 15) * 4 + (lane >> 4);
    const float invn = 1.f / (float)NNODES;
    float mean = stats[lane] * invn;
    float var = stats[64 + lane] * invn - mean * mean;
    float rs = rsqrtf(var + BN_EPS);
    float ga = gamma[lane], be = beta[lane];
    float bF = 0.f, bS = 0.f;
    if (next_layer >= 0) {
        bF = bcf[next_layer * HID + lane];
        bS = bcs[next_layer * HID + lane];
    }
    for (int n = wid; n < NNODES; n += nw) {
        float v = h[n * HID + lane] + agg[n * HID + lane];
        float y = (v - mean) * rs * ga + be;
        if (relu) y = fmaxf(y, 0.f);
        h[n * HID + lane] = y;
        h_bf[n * HID + lane] = f2bf(y);
        if (next_layer >= 0) {
            float af = bF, as = bS;
            #pragma unroll 8
            for (int k = 0; k < HID; ++k) {
                float yk = __shfl(y, k, 64);
                af = fmaf(yk, Wl[0][k][lane], af);
                as = fmaf(yk, Wl[1][k][lane], as);
            }
            Ttgt[(long)n * 128 + pg] = af;
            Ttgt[(long)n * 128 + 64 + pg] = as;
        }
    }
}

extern "C" void kernel_launch(void* const* d_in, const int* in_sizes, int n_in,
                              void* d_out, int out_size, void* d_ws, size_t ws_size,
                              hipStream_t stream) {
    const float* x    = (const float*)d_in[0];
    const float* ea   = (const float*)d_in[1];
    const int*   eidx = (const int*)d_in[2];
    const float* W1   = (const float*)d_in[3];
    const float* b1   = (const float*)d_in[4];
    const float* W2   = (const float*)d_in[5];
    const float* b2   = (const float*)d_in[6];
    const float* Wf   = (const float*)d_in[7];
    const float* bf   = (const float*)d_in[8];
    const float* Ws   = (const float*)d_in[9];
    const float* bs   = (const float*)d_in[10];
    const float* gamma= (const float*)d_in[11];
    const float* beta = (const float*)d_in[12];
    float* h = (float*)d_out; // [NNODES, 64]

    // workspace layout (256 B aligned sections)
    char* wb = (char*)d_ws;
    auto align = [&]() { wb = (char*)(((size_t)wb + 255) & ~(size_t)255); };
    ushort* Bpack = (ushort*)wb;  wb += 3 * 8 * 4 * 512 * sizeof(ushort); align(); // 96 KB
    float* bcf   = (float*)wb;    wb += 3 * HID * sizeof(float);
    float* bcs   = (float*)wb;    wb += 3 * HID * sizeof(float);
    float* stats = (float*)wb;    wb += 3 * 2 * HID * sizeof(float); align();
    int* deg     = (int*)wb;      wb += NNODES * sizeof(int);
    int* rowptr  = (int*)wb;      wb += (NNODES + 1) * sizeof(int);
    int* cursor  = (int*)wb;      wb += NNODES * sizeof(int);
    int* bsum    = (int*)wb;      wb += 256 * sizeof(int);
    int* bbase   = (int*)wb;      wb += 256 * sizeof(int); align();
    int* eorig   = (int*)wb;      wb += NEDGES * sizeof(int);          // 3.2 MB
    int* srcs    = (int*)wb;      wb += NEDGES * sizeof(int);          // 3.2 MB
    align();
    float* Ttgt  = (float*)wb;    wb += (size_t)NNODES * 128 * sizeof(float); // 25.6 MB
    float* agg   = (float*)wb;    wb += (size_t)NNODES * HID * sizeof(float); // 12.8 MB
    ushort* h_bf = (ushort*)wb;   wb += (size_t)NNODES * HID * sizeof(ushort); // 6.4 MB
    ushort* eab_s= (ushort*)wb;   wb += (size_t)NEDGES * 64 * sizeof(ushort);  // 102.4 MB

    // --- setup: weights+stats, CSR sort, embed+proj0 ---
    prep<<<7, 256, 0, stream>>>(W2, b2, Wf, bf, Ws, bs, Bpack, bcf, bcs, stats);

    hipMemsetAsync(deg, 0, NNODES * sizeof(int), stream);
    k_hist<<<(NEDGES + 255) / 256, 256, 0, stream>>>(eidx, deg);
    k_blocksum<<<196, 256, 0, stream>>>(deg, bsum);
    k_scanbase<<<1, 256, 0, stream>>>(bsum, bbase, rowptr);
    k_writerow<<<196, 256, 0, stream>>>(deg, bbase, rowptr, cursor);
    k_scatterA<<<(NEDGES + 255) / 256, 256, 0, stream>>>(eidx, cursor, eorig, srcs);
    k_scatterB<<<(NEDGES * 8 + 255) / 256, 256, 0, stream>>>(ea, eorig, eab_s);

    embed_proj<<<1024, 256, 0, stream>>>(x, W1, b1, Wf, Ws, bcf, bcs, h, h_bf, Ttgt);

    for (int i = 0; i < 3; ++i) {
        edge_kernel<<<2048, 256, 0, stream>>>(eab_s, srcs, rowptr, h_bf, h, Ttgt,
                                              Bpack + i * 16384, agg, stats + i * 128);
        bn_apply_proj<<<1024, 256, 0, stream>>>(h, agg, stats + i * 128, gamma + i * HID,
                                                beta + i * HID, h_bf, Wf, Ws, bcf, bcs,
                                                Ttgt, (i < 2) ? 1 : 0,
                                                (i < 2) ? (i + 1) : -1);
    }
}